// Round 14
// baseline (281.995 us; speedup 1.0000x reference)
//
#include <hip/hip_runtime.h>
#include <hip/hip_fp16.h>

// GCN 2-layer: N=200000, E=6400000, 14 -> 16(relu) -> 2.
// Round 26: channel-split layer-1 (launch-only; cooperative REVERTED --
// round-25 failed correctness, most plausibly hipLaunchCooperativeKernel vs
// the harness's graph capture; no algorithmic race existed).
// Round-12 arithmetic: agg1f's 191MB FETCH = LRU capacity miss on the 6.4MB
// xph region (hit ~ 4/6.4 = 62%). Fix along the CHANNEL axis, not phases:
//   - xph split into two PHYSICAL planes (ch0-7, ch8-15), 3.2MB each --
//     each fits a 4MB XCD L2 (shared 64B lines would cache both halves,
//     hence separate planes, not strided halves).
//   - k_agg1h: gathers plane0 only, writes 8-float partial agg0 (6.4MB,
//     1/4 of the old partial round-trip).
//   - k_agg1n: gathers plane1, folds agg0 + self + ovf, fused MLP.
//   - agg0 overlays dead binned; sort's fused prep writes both planes.
// Pipeline: init -> binA -> sort(+dinv+planes) -> agg1h -> agg1n -> agg2.

constexpr int NN = 200000;
constexpr int NE = 6400000;
constexpr int IC = 14;
constexpr int HC = 16;
constexpr int OC = 2;

constexpr int NBK = 392;                   // buckets of 512 dst nodes
constexpr int NSUB = 8;                    // sub-segments per bucket (= XCD id)
constexpr int SCAP = 2816;                 // per (sub,bucket) cap: mean 2058 + 16.7 sigma
constexpr int NSEG = NSUB * NBK;           // 3136 segments
constexpr int CCAP = NSUB * SCAP;          // 22528 csr per-bucket capacity
constexpr int SPT = (SCAP + 1023) / 1024;  // 3 reg slots per (thread, segment)
constexpr int TILE = 5120;                 // edges per binA tile
constexpr int BTH = 512;                   // binA threads
constexpr int IPT = TILE / BTH;            // 10
constexpr int IPT2 = IPT / 2;              // 5 pair-loads per thread
constexpr int NTILE = NE / TILE;           // 1250
constexpr int OVFCAP = 65536;
constexpr int NM = NN / 32;                // 6250 blocks (32 nodes per block)
constexpr int GSTR = 16;                   // gcur stride: 1 counter per 64B line

typedef unsigned long long ull;
typedef float f4v __attribute__((ext_vector_type(4)));

__device__ __forceinline__ int phase_of(unsigned src) {
    return src >= 100000u ? (src >= 150000u ? 3 : 2) : (src >= 50000u ? 1 : 0);
}

// Physical XCD id (0..7). Affinity heuristic only -- correctness never
// depends on the value (G16): binA has the overflow path.
__device__ __forceinline__ int xcc_id() {
    int x;
    asm volatile("s_getreg_b32 %0, hwreg(HW_REG_XCC_ID)" : "=s"(x));
    return x & 7;
}

// accumulate 8 halves (one 16B plane row) into av[8]
__device__ __forceinline__ void acc8(float* av, uint4 u) {
    float2 f0 = __half22float2(*(__half2*)&u.x);
    float2 f1 = __half22float2(*(__half2*)&u.y);
    float2 f2 = __half22float2(*(__half2*)&u.z);
    float2 f3 = __half22float2(*(__half2*)&u.w);
    av[0] += f0.x; av[1] += f0.y; av[2] += f1.x; av[3] += f1.y;
    av[4] += f2.x; av[5] += f2.y; av[6] += f3.x; av[7] += f3.y;
}

// init gcur (padded) + ovf counter + dtype flag
__global__ void k_init(int* __restrict__ gcur, const void* __restrict__ ei,
                       int* __restrict__ flag) {
    int i = blockIdx.x * blockDim.x + threadIdx.x;
    if (i < NSEG) gcur[i * GSTR] = i * SCAP;
    else if (i <= NSEG + 4) gcur[i * GSTR] = 0;  // ovf counter (+spare)
    if (i == 500) {  // one thread sniffs edge dtype
        const ull* p = (const ull*)ei;
        ull acc = 0ULL;
        for (int k = 0; k < 64; ++k) acc |= (p[k] >> 32);
        *flag = (acc == 0ULL) ? 1 : 0;  // 1 => int64 indices, 0 => int32
    }
}

// Bin edges by dst>>9 into per-(sub,bucket) global segments, sub = XCC_ID.
// All edge words preloaded to registers (20 independent loads in flight),
// then the atomic/pack loop runs against warm registers. LDS-staged for
// coalesced segment write-out.
__global__ __launch_bounds__(BTH, 6) void k_binA(const void* __restrict__ ei,
                                                 const int* __restrict__ flag,
                                                 int* __restrict__ gcur,
                                                 unsigned* __restrict__ binned,
                                                 ull* __restrict__ ovf) {
    __shared__ int hist[NBK];
    __shared__ int lofs[NBK];
    __shared__ int gofs[NBK];
    __shared__ int wsum[BTH / 64];
    __shared__ unsigned stage[TILE];

    int t = threadIdx.x;
    int fl = *flag;
    int tile0 = blockIdx.x * TILE;
    int segbase = xcc_id() * NBK;

    if (t < NBK) hist[t] = 0;
    __syncthreads();

    // preload: 20 independent dword loads (int64 path reads low dwords only)
    int dbuf[IPT], sbuf[IPT];
    const int* pw = (const int*)ei;
    if (fl) {
#pragma unroll
        for (int k = 0; k < IPT2; ++k) {
            int e = tile0 + k * (2 * BTH) + 2 * t;
            dbuf[2 * k] = pw[2 * (NE + e)];
            dbuf[2 * k + 1] = pw[2 * (NE + e) + 2];
            sbuf[2 * k] = pw[2 * e];
            sbuf[2 * k + 1] = pw[2 * e + 2];
        }
    } else {
#pragma unroll
        for (int k = 0; k < IPT2; ++k) {
            int e = tile0 + k * (2 * BTH) + 2 * t;
            uint2 dd = *(const uint2*)(pw + NE + e);
            uint2 ss = *(const uint2*)(pw + e);
            dbuf[2 * k] = (int)dd.x;
            dbuf[2 * k + 1] = (int)dd.y;
            sbuf[2 * k] = (int)ss.x;
            sbuf[2 * k + 1] = (int)ss.y;
        }
    }

    // atomic rank capture from registers.
    // pk = (dlow<<18)|src ; ra = (rank<<9)|bucket  (rank<5120 fits 13 bits)
    unsigned pk[IPT];
    unsigned ra[IPT];
#pragma unroll
    for (int k = 0; k < IPT; ++k) {
        int d = dbuf[k];
        int b = d >> 9;
        int r = atomicAdd(&hist[b], 1);
        pk[k] = ((unsigned)(d & 511) << 18) | (unsigned)sbuf[k];
        ra[k] = ((unsigned)r << 9) | (unsigned)b;
    }
    __syncthreads();

    // exclusive scan of 392 counts: pair-sum + 64-lane shfl scan + wave combine
    int h0 = 0, h1 = 0, p = 0;
    if (t < NBK / 2) {
        h0 = hist[2 * t];
        h1 = hist[2 * t + 1];
        p = h0 + h1;
    }
    int lane = t & 63;
    int w = t >> 6;
    int incl = p;
#pragma unroll
    for (int off = 1; off < 64; off <<= 1) {
        int v = __shfl_up(incl, off, 64);
        if (lane >= off) incl += v;
    }
    if (lane == 63) wsum[w] = incl;
    __syncthreads();
    int wbase = 0;
#pragma unroll
    for (int ww = 0; ww < BTH / 64; ++ww) wbase += (ww < w) ? wsum[ww] : 0;
    int ex = wbase + incl - p;
    if (t < NBK / 2) {
        lofs[2 * t] = ex;
        lofs[2 * t + 1] = ex + h0;
    }
    if (t < NBK) gofs[t] = atomicAdd(&gcur[(segbase + t) * GSTR], hist[t]);
    __syncthreads();

    // stage from regs at lofs[bucket] + rank (no global loads)
#pragma unroll
    for (int k = 0; k < IPT; ++k) {
        int b = (int)(ra[k] & 511u);
        int r = (int)(ra[k] >> 9);
        stage[lofs[b] + r] = pk[k];
    }
    __syncthreads();

    // coalesced write-out; bucket of slot i via seeded search on lofs
    for (int i = t; i < TILE; i += BTH) {
        int b = (i * 313) >> 12;  // ~ i / 13.06 (mean slots per bucket)
        if (b > NBK - 1) b = NBK - 1;
        while (b < NBK - 1 && lofs[b + 1] <= i) ++b;
        while (lofs[b] > i) --b;
        unsigned pack = stage[i];
        int seg = segbase + b;
        int dest = gofs[b] + (i - lofs[b]);
        if (dest < (seg + 1) * SCAP) {
            binned[dest] = pack;
        } else {  // overflow (never in practice)
            int op = atomicAdd(&gcur[NSEG * GSTR], 1);
            if (op < OVFCAP) {
                int d = (b << 9) | (int)(pack >> 18);
                int s = (int)(pack & 0x3FFFF);
                ovf[op] = ((ull)d << 32) | (unsigned)s;
            }
        }
    }
}

// bucket-local counting sort over 8 sub-segments, key = (dlow<<2)|phase(src).
// Single pass: rank captured from cnt atomic, (src, rank|key) in regs;
// scatter into LDS stage; coalesced uint4 write-out. Computes dinv and packed
// phase counts. Fused prep: after write-out, 2 threads/node write the node's
// TWO xph planes (fp16 dinv*x; plane0 = ch0-7, plane1 = ch8-13 + pad).
__global__ __launch_bounds__(1024, 4) void k_sort(const int* __restrict__ gcur,
                                                  const unsigned* __restrict__ binned,
                                                  const ull* __restrict__ ovf,
                                                  const float* __restrict__ x,
                                                  unsigned* __restrict__ csr,
                                                  float* __restrict__ dinv,
                                                  int* __restrict__ rsg,
                                                  unsigned* __restrict__ spl,
                                                  __half* __restrict__ xph0,
                                                  __half* __restrict__ xph1) {
    __shared__ int cnt[2048];
    __shared__ int excl[2048];
    __shared__ int wsum[16];
    __shared__ int nseg[NSUB];
    __shared__ float sdv[512];
    __shared__ unsigned stage[CCAP];      // 88KB sorted bucket staging
    int b = blockIdx.x;
    int t = threadIdx.x;
    cnt[t] = 0;
    cnt[t + 1024] = 0;
    if (t < NSUB) {
        int seg = t * NBK + b;
        nseg[t] = min(gcur[seg * GSTR] - seg * SCAP, SCAP);
    }
    __syncthreads();
    int nov = min(gcur[NSEG * GSTR], OVFCAP);

    // single pass: load + key + rank capture; held in regs (static indexing)
    unsigned srcv[NSUB * SPT];
    unsigned rkv[NSUB * SPT];
#pragma unroll
    for (int s = 0; s < NSUB; ++s) {
        int n = nseg[s];
        int sb = (s * NBK + b) * SCAP;
#pragma unroll
        for (int k = 0; k < SPT; ++k) {
            int i = k * 1024 + t;
            rkv[s * SPT + k] = 0xFFFFFFFFu;
            if (i < n) {
                unsigned pack = binned[sb + i];
                unsigned src = pack & 0x3FFFFu;
                int key = ((int)(pack >> 18) << 2) | phase_of(src);
                int r = atomicAdd(&cnt[key], 1);
                srcv[s * SPT + k] = src;
                rkv[s * SPT + k] = ((unsigned)r << 11) | (unsigned)key;
            }
        }
    }
    __syncthreads();

    // exclusive scan of 2048 counts: pair-sum + 1024-lane scan (16 waves)
    int h0 = cnt[2 * t];
    int h1 = cnt[2 * t + 1];
    int p = h0 + h1;
    int lane = t & 63;
    int w = t >> 6;
    int incl = p;
#pragma unroll
    for (int off = 1; off < 64; off <<= 1) {
        int v = __shfl_up(incl, off, 64);
        if (lane >= off) incl += v;
    }
    if (lane == 63) wsum[w] = incl;
    __syncthreads();
    int wbase = 0;
#pragma unroll
    for (int ww = 0; ww < 16; ++ww) wbase += (ww < w) ? wsum[ww] : 0;
    int ex = wbase + incl - p;
    excl[2 * t] = ex;
    excl[2 * t + 1] = ex + h0;
    __syncthreads();

    // scatter into LDS stage (bucket-relative positions)
#pragma unroll
    for (int c = 0; c < NSUB * SPT; ++c) {
        unsigned rk = rkv[c];
        if (rk != 0xFFFFFFFFu) {
            int key = (int)(rk & 0x7FFu);
            int r = (int)(rk >> 11);
            stage[excl[key] + r] = srcv[c];
        }
    }

    // per-node stats (cnt/excl are stable; independent of stage)
    if (t < 512) {
        int g = (b << 9) + t;
        if (g < NN) {
            int c0 = cnt[4 * t];
            int c1 = cnt[4 * t + 1];
            int c2 = cnt[4 * t + 2];
            int c3 = cnt[4 * t + 3];
            int extra = 0;
            for (int k = 0; k < nov; ++k) extra += ((int)(ovf[k] >> 32) == g);
            float dv = rsqrtf((float)(c0 + c1 + c2 + c3 + extra) + 1.0f);
            dinv[g] = dv;
            sdv[t] = dv;
            rsg[g] = b * CCAP + excl[4 * t];                 // csr row start (absolute)
            spl[g] = (unsigned)c0 | ((unsigned)c1 << 8) |
                     ((unsigned)c2 << 16) | ((unsigned)c3 << 24);
        }
    }
    __syncthreads();

    // coalesced uint4 write-out (pad to 16B; garbage pad stays in-bucket)
    int total = excl[2047] + cnt[2047];
    int tot4 = (total + 3) >> 2;
    const uint4* st4 = (const uint4*)stage;
    uint4* csr4 = (uint4*)(csr + (size_t)b * CCAP);
#pragma unroll
    for (int k = 0; k < (CCAP / 4 + 1023) / 1024; ++k) {
        int i4 = k * 1024 + t;
        if (i4 < tot4) csr4[i4] = st4[i4];
    }

    // fused prep: both planes for this block's 512 nodes (2 threads/node,
    // plane = t&1, 8 halves each). sdv synced by the pre-write-out barrier.
    {
        int n512 = t >> 1;
        int g = (b << 9) + n512;
        if (g < NN) {
            float dv = sdv[n512];
            int pl = t & 1;
            int cb = 8 * pl;
            const float* xr = x + (size_t)g * IC;
            float v[8];
#pragma unroll
            for (int c = 0; c < 8; c += 2) {
                int ch = cb + c;
                if (ch + 1 < IC) {
                    float2 xx = *(const float2*)(xr + ch);
                    v[c] = dv * xx.x;
                    v[c + 1] = dv * xx.y;
                } else {
                    v[c] = 0.0f;
                    v[c + 1] = 0.0f;
                }
            }
            __half2 p0 = __floats2half2_rn(v[0], v[1]);
            __half2 p1 = __floats2half2_rn(v[2], v[3]);
            __half2 p2 = __floats2half2_rn(v[4], v[5]);
            __half2 p3 = __floats2half2_rn(v[6], v[7]);
            uint4 pk4;
            pk4.x = *(unsigned*)&p0;
            pk4.y = *(unsigned*)&p1;
            pk4.z = *(unsigned*)&p2;
            pk4.w = *(unsigned*)&p3;
            __half* dst = (pl ? xph1 : xph0) + (size_t)g * 8;
            *(uint4*)dst = pk4;
        }
    }
}

// Layer-1 half A: gather PLANE 0 only (3.2MB, L2-resident per XCD) over the
// full csr row. 8 lanes per node = pure edge split; depth-1 pipeline;
// shfl_xor(1,2,4) tree; lanes 0/1 nt-store the 8-float partial agg0 row.
__global__ __launch_bounds__(256) void k_agg1h(const int* __restrict__ rsg,
                                               const unsigned* __restrict__ spl,
                                               const unsigned* __restrict__ csr,
                                               const __half* __restrict__ xp0,
                                               float* __restrict__ agg0) {
    int t = threadIdx.x;
    int g = t >> 3;
    int h = t & 7;
    int i = blockIdx.x * 32 + g;   // NN = 6250*32 exactly
    unsigned sp = spl[i];
    int tot = (int)(sp & 255u) + (int)((sp >> 8) & 255u) +
              (int)((sp >> 16) & 255u) + (int)(sp >> 24);
    int beg = rsg[i];
    int end = beg + tot;

    float av[8];
#pragma unroll
    for (int c = 0; c < 8; ++c) av[c] = 0.0f;
    int j = beg + h;
    int s0 = (j < end) ? (int)csr[j] : -1;
    int s1 = (j + 8 < end) ? (int)csr[j + 8] : -1;
    while (j < end) {
        int jn = j + 16;
        int n0 = (jn < end) ? (int)csr[jn] : -1;
        int n1 = (jn + 8 < end) ? (int)csr[jn + 8] : -1;
        uint4 u0 = *(const uint4*)(xp0 + (size_t)s0 * 8);
        acc8(av, u0);
        if (s1 >= 0) {
            uint4 u1 = *(const uint4*)(xp0 + (size_t)s1 * 8);
            acc8(av, u1);
        }
        s0 = n0;
        s1 = n1;
        j = jn;
    }
#pragma unroll
    for (int c = 0; c < 8; ++c) av[c] += __shfl_xor(av[c], 1);
#pragma unroll
    for (int c = 0; c < 8; ++c) av[c] += __shfl_xor(av[c], 2);
#pragma unroll
    for (int c = 0; c < 8; ++c) av[c] += __shfl_xor(av[c], 4);
    if (h == 0) {
        f4v r0 = {av[0], av[1], av[2], av[3]};
        __builtin_nontemporal_store(r0, (f4v*)(agg0 + (size_t)i * 8));
    } else if (h == 1) {
        f4v r1 = {av[4], av[5], av[6], av[7]};
        __builtin_nontemporal_store(r1, (f4v*)(agg0 + (size_t)i * 8 + 4));
    }
}

// Layer-1 half B + MLP: gather PLANE 1 (3.2MB, L2-resident), fold agg0
// partial + self rows (both planes) + ovf fixup, then the fused MLP.
// 8 lanes per node; shfl_xor(1,2,4) tree leaves the plane-1 sum on all
// lanes; lane h==0 assembles the sAgg row; 2 hidden units per lane,
// shfl_xor(1,2,4) combines the output dot. Writes h2bp/selfout (3.2MB).
__global__ __launch_bounds__(256) void k_agg1n(const int* __restrict__ rsg,
                                               const unsigned* __restrict__ spl,
                                               const unsigned* __restrict__ csr,
                                               const __half* __restrict__ xp0,
                                               const __half* __restrict__ xp1,
                                               const float* __restrict__ agg0,
                                               const int* __restrict__ gcur,
                                               const ull* __restrict__ ovf,
                                               const float* __restrict__ dinv,
                                               const float* __restrict__ W1,
                                               const float* __restrict__ b1,
                                               const float* __restrict__ W2,
                                               const float* __restrict__ b2,
                                               float2* __restrict__ h2bp,
                                               float2* __restrict__ selfout) {
    __shared__ float sW1[IC * HC];
    __shared__ float sb1[HC];
    __shared__ float sW2[HC * OC];
    __shared__ float sb2[OC];
    __shared__ float sAgg[32][17];  // +1 pad: spread rows across banks
    int t = threadIdx.x;
    if (t < IC * HC) sW1[t] = W1[t];
    if (t < HC) sb1[t] = b1[t];
    if (t < HC * OC) sW2[t] = W2[t];
    if (t < OC) sb2[t] = b2[t];

    int g = t >> 3;
    int h = t & 7;
    int i = blockIdx.x * 32 + g;   // NN = 6250*32 exactly
    unsigned sp = spl[i];
    int tot = (int)(sp & 255u) + (int)((sp >> 8) & 255u) +
              (int)((sp >> 16) & 255u) + (int)(sp >> 24);
    int beg = rsg[i];
    int end = beg + tot;

    float av[8];
#pragma unroll
    for (int c = 0; c < 8; ++c) av[c] = 0.0f;
    int j = beg + h;
    int s0 = (j < end) ? (int)csr[j] : -1;
    int s1 = (j + 8 < end) ? (int)csr[j + 8] : -1;
    while (j < end) {
        int jn = j + 16;
        int n0 = (jn < end) ? (int)csr[jn] : -1;
        int n1 = (jn + 8 < end) ? (int)csr[jn + 8] : -1;
        uint4 u0 = *(const uint4*)(xp1 + (size_t)s0 * 8);
        acc8(av, u0);
        if (s1 >= 0) {
            uint4 u1 = *(const uint4*)(xp1 + (size_t)s1 * 8);
            acc8(av, u1);
        }
        s0 = n0;
        s1 = n1;
        j = jn;
    }
#pragma unroll
    for (int c = 0; c < 8; ++c) av[c] += __shfl_xor(av[c], 1);
#pragma unroll
    for (int c = 0; c < 8; ++c) av[c] += __shfl_xor(av[c], 2);
#pragma unroll
    for (int c = 0; c < 8; ++c) av[c] += __shfl_xor(av[c], 4);

    float dv = dinv[i];
    if (h == 0) {
        // plane-1 self row onto the (complete) plane-1 sum
        uint4 us1 = *(const uint4*)(xp1 + (size_t)i * 8);
        acc8(av, us1);
        // plane-0: agg0 partial (one-shot stream) + self row
        float a0[8];
        f4v p0 = __builtin_nontemporal_load((const f4v*)(agg0 + (size_t)i * 8));
        f4v p1 = __builtin_nontemporal_load((const f4v*)(agg0 + (size_t)i * 8 + 4));
        a0[0] = p0.x; a0[1] = p0.y; a0[2] = p0.z; a0[3] = p0.w;
        a0[4] = p1.x; a0[5] = p1.y; a0[6] = p1.z; a0[7] = p1.w;
        uint4 us0 = *(const uint4*)(xp0 + (size_t)i * 8);
        acc8(a0, us0);
        // overflow fixup (nov==0 in practice), both planes
        int nov = min(gcur[NSEG * GSTR], OVFCAP);
        for (int k = 0; k < nov; ++k) {
            ull e = ovf[k];
            if ((int)(e >> 32) == i) {
                int s = (int)(e & 0xFFFFFFFFu);
#pragma unroll
                for (int c = 0; c < 8; ++c) {
                    a0[c] += __half2float(xp0[(size_t)s * 8 + c]);
                    av[c] += __half2float(xp1[(size_t)s * 8 + c]);
                }
            }
        }
#pragma unroll
        for (int c = 0; c < 8; ++c) {
            sAgg[g][c] = dv * a0[c];
            sAgg[g][8 + c] = dv * av[c];
        }
    }
    __syncthreads();

    // MLP: lane l8 = t&7 computes hidden units 2*l8, 2*l8+1 (sAgg row is an
    // LDS broadcast across the node's 8 lanes).
    int l8 = t & 7;
    float o0 = 0.0f, o1 = 0.0f;
#pragma unroll
    for (int f2 = 0; f2 < 2; ++f2) {
        int f = 2 * l8 + f2;
        float a = sb1[f];
#pragma unroll
        for (int c = 0; c < IC; ++c) a = fmaf(sAgg[g][c], sW1[c * HC + f], a);
        a = fmaxf(a, 0.0f);
        o0 = fmaf(a, sW2[f * OC + 0], o0);
        o1 = fmaf(a, sW2[f * OC + 1], o1);
    }
    o0 += __shfl_xor(o0, 1);
    o1 += __shfl_xor(o1, 1);
    o0 += __shfl_xor(o0, 2);
    o1 += __shfl_xor(o1, 2);
    o0 += __shfl_xor(o0, 4);
    o1 += __shfl_xor(o1, 4);
    if (l8 == 0) {
        h2bp[i] = make_float2(o0 * dv, o1 * dv);  // dinv-prescaled for layer 2
        selfout[i] = make_float2(o0 * dv * dv + sb2[0], o1 * dv * dv + sb2[1]);
    }
}

// layer-2: out[i] = selfout[i] + dinv[i] * (sum h2bp[src] + ovf matches).
// 8 lanes per node, depth-1 csr pipeline; shfl_xor(1,2,4) combine.
__global__ __launch_bounds__(256) void k_agg2(const int* __restrict__ rsg,
                                              const unsigned* __restrict__ spl,
                                              const unsigned* __restrict__ csr,
                                              const int* __restrict__ gcur,
                                              const ull* __restrict__ ovf,
                                              const float* __restrict__ dinv,
                                              const float2* __restrict__ h2bp,
                                              const float2* __restrict__ selfout,
                                              float2* __restrict__ out) {
    int tt = blockIdx.x * 256 + threadIdx.x;
    int i = tt >> 3;
    int h = tt & 7;
    if (i >= NN) return;
    unsigned sp = spl[i];
    int tot = (int)(sp & 255u) + (int)((sp >> 8) & 255u) +
              (int)((sp >> 16) & 255u) + (int)(sp >> 24);
    int beg = rsg[i];
    int end = beg + tot;
    float ax = 0.0f, ay = 0.0f;
    int j = beg + h;
    int s0 = (j < end) ? (int)csr[j] : -1;
    int s1 = (j + 8 < end) ? (int)csr[j + 8] : -1;
    while (j < end) {
        int jn = j + 16;
        int n0 = (jn < end) ? (int)csr[jn] : -1;
        int n1 = (jn + 8 < end) ? (int)csr[jn + 8] : -1;
        float2 h0 = h2bp[s0];
        ax += h0.x;
        ay += h0.y;
        if (s1 >= 0) {
            float2 h1 = h2bp[s1];
            ax += h1.x;
            ay += h1.y;
        }
        s0 = n0;
        s1 = n1;
        j = jn;
    }
    ax += __shfl_xor(ax, 1);
    ay += __shfl_xor(ay, 1);
    ax += __shfl_xor(ax, 2);
    ay += __shfl_xor(ay, 2);
    ax += __shfl_xor(ax, 4);
    ay += __shfl_xor(ay, 4);
    if (h == 0) {
        // overflow fixup (nov==0 in practice); h2bp already dinv[src]-prescaled
        int nov = min(gcur[NSEG * GSTR], OVFCAP);
        for (int k = 0; k < nov; ++k) {
            ull e = ovf[k];
            if ((int)(e >> 32) == i) {
                float2 hh = h2bp[(int)(e & 0xFFFFFFFFu)];
                ax += hh.x;
                ay += hh.y;
            }
        }
        float dv = dinv[i];
        float2 so = selfout[i];
        out[i] = make_float2(so.x + dv * ax, so.y + dv * ay);
    }
}

extern "C" void kernel_launch(void* const* d_in, const int* in_sizes, int n_in,
                              void* d_out, int out_size, void* d_ws, size_t ws_size,
                              hipStream_t stream) {
    const float* x = (const float*)d_in[0];
    const void* ei = d_in[1];
    // d_in[2] = edge_attr (unused)
    const float* W1 = (const float*)d_in[3];
    const float* b1 = (const float*)d_in[4];
    const float* W2 = (const float*)d_in[5];
    const float* b2 = (const float*)d_in[6];
    float* out = (float*)d_out;

    ull* ovf = (ull*)d_ws;                              // OVFCAP       (0.5MB)
    int* gcur = (int*)(ovf + OVFCAP);                   // (NSEG+5)*16 ints
    int* flag = gcur + (NSEG + 5) * GSTR;               // 4
    int* rsg = flag + 4;                                // NN
    unsigned* spl = (unsigned*)(rsg + NN);              // NN
    float* dinv = (float*)(spl + NN);                   // NN
    __half* xph0 = (__half*)(dinv + NN);                // NN*8 halves (3.2MB)
    __half* xph1 = xph0 + (size_t)NN * 8;               // NN*8 halves (3.2MB)
    float2* h2bp = (float2*)(xph1 + (size_t)NN * 8);    // NN
    float2* selfout = h2bp + NN;                        // NN
    unsigned* binned = (unsigned*)(selfout + NN);       // NSEG*SCAP    (35.3MB)
    float* agg0 = (float*)binned;                       // NN*8 f32 (6.4MB), overlays
                                                        // binned (dead after k_sort)
    unsigned* csr = binned + (size_t)NSEG * SCAP;       // NBK*CCAP     (35.3MB)

    k_init<<<(NSEG + 5 + 255) / 256, 256, 0, stream>>>(gcur, ei, flag);
    k_binA<<<NTILE, BTH, 0, stream>>>(ei, flag, gcur, binned, ovf);
    k_sort<<<NBK, 1024, 0, stream>>>(gcur, binned, ovf, x, csr, dinv, rsg, spl,
                                     xph0, xph1);
    k_agg1h<<<NM, 256, 0, stream>>>(rsg, spl, csr, xph0, agg0);
    k_agg1n<<<NM, 256, 0, stream>>>(rsg, spl, csr, xph0, xph1, agg0, gcur, ovf,
                                    dinv, W1, b1, W2, b2, h2bp, selfout);
    k_agg2<<<(NN * 8 + 255) / 256, 256, 0, stream>>>(rsg, spl, csr, gcur, ovf, dinv,
                                                     h2bp, selfout, (float2*)out);
}

// Round 15
// 270.296 us; speedup vs baseline: 1.0433x; 1.0433x over previous
//
#include <hip/hip_runtime.h>
#include <hip/hip_fp16.h>

// GCN 2-layer: N=200000, E=6400000, 14 -> 16(relu) -> 2.
// Round 27: revert layer-1 to the round-24 single-kernel agg1f. Measured
// ranking of layer-1 structures: agg1f 70us (BW-bound, 2.86TB/s miss
// traffic) < partial-split ~85us < channel-split ~90us (latency-bound at
// 0.94TB/s despite near-compulsory FETCH). Random-gather BW beats split
// locality here. This round's delta goes to binA:
//   - int64 path now issues 10x16B ulonglong2 pair loads (2 indices each,
//     low dword extracted on arrival) instead of 20x4B dword picks --
//     half the request count / waitcnt tags against ~300cy L3 latency.
//     Line traffic unchanged (all lines touched; edge list L3-resident).
// Pipeline: init -> binA -> sort(+dinv+xph) -> agg1f -> agg2.

constexpr int NN = 200000;
constexpr int NE = 6400000;
constexpr int IC = 14;
constexpr int HC = 16;
constexpr int OC = 2;

constexpr int NBK = 392;                   // buckets of 512 dst nodes
constexpr int NSUB = 8;                    // sub-segments per bucket (= XCD id)
constexpr int SCAP = 2816;                 // per (sub,bucket) cap: mean 2058 + 16.7 sigma
constexpr int NSEG = NSUB * NBK;           // 3136 segments
constexpr int CCAP = NSUB * SCAP;          // 22528 csr per-bucket capacity
constexpr int SPT = (SCAP + 1023) / 1024;  // 3 reg slots per (thread, segment)
constexpr int TILE = 5120;                 // edges per binA tile
constexpr int BTH = 512;                   // binA threads
constexpr int IPT = TILE / BTH;            // 10
constexpr int IPT2 = IPT / 2;              // 5 pair-loads per thread
constexpr int NTILE = NE / TILE;           // 1250
constexpr int OVFCAP = 65536;
constexpr int NM = NN / 32;                // 6250 blocks (32 nodes per block)
constexpr int GSTR = 16;                   // gcur stride: 1 counter per 64B line

typedef unsigned long long ull;
typedef float f4v __attribute__((ext_vector_type(4)));

__device__ __forceinline__ int phase_of(unsigned src) {
    return src >= 100000u ? (src >= 150000u ? 3 : 2) : (src >= 50000u ? 1 : 0);
}

// Physical XCD id (0..7). Affinity heuristic only -- correctness never
// depends on the value (G16): binA has the overflow path.
__device__ __forceinline__ int xcc_id() {
    int x;
    asm volatile("s_getreg_b32 %0, hwreg(HW_REG_XCC_ID)" : "=s"(x));
    return x & 7;
}

// accumulate 8 halves (one 16B xph half-row) into av[8]
__device__ __forceinline__ void acc8(float* av, uint4 u) {
    float2 f0 = __half22float2(*(__half2*)&u.x);
    float2 f1 = __half22float2(*(__half2*)&u.y);
    float2 f2 = __half22float2(*(__half2*)&u.z);
    float2 f3 = __half22float2(*(__half2*)&u.w);
    av[0] += f0.x; av[1] += f0.y; av[2] += f1.x; av[3] += f1.y;
    av[4] += f2.x; av[5] += f2.y; av[6] += f3.x; av[7] += f3.y;
}

// init gcur (padded) + ovf counter + dtype flag
__global__ void k_init(int* __restrict__ gcur, const void* __restrict__ ei,
                       int* __restrict__ flag) {
    int i = blockIdx.x * blockDim.x + threadIdx.x;
    if (i < NSEG) gcur[i * GSTR] = i * SCAP;
    else if (i <= NSEG + 4) gcur[i * GSTR] = 0;  // ovf counter (+spare)
    if (i == 500) {  // one thread sniffs edge dtype
        const ull* p = (const ull*)ei;
        ull acc = 0ULL;
        for (int k = 0; k < 64; ++k) acc |= (p[k] >> 32);
        *flag = (acc == 0ULL) ? 1 : 0;  // 1 => int64 indices, 0 => int32
    }
}

// Bin edges by dst>>9 into per-(sub,bucket) global segments, sub = XCC_ID.
// All edge words preloaded to registers (16B pair loads -> 10 requests in
// flight), then the atomic/pack loop runs against warm registers. LDS-staged
// for coalesced segment write-out.
__global__ __launch_bounds__(BTH, 6) void k_binA(const void* __restrict__ ei,
                                                 const int* __restrict__ flag,
                                                 int* __restrict__ gcur,
                                                 unsigned* __restrict__ binned,
                                                 ull* __restrict__ ovf) {
    __shared__ int hist[NBK];
    __shared__ int lofs[NBK];
    __shared__ int gofs[NBK];
    __shared__ int wsum[BTH / 64];
    __shared__ unsigned stage[TILE];

    int t = threadIdx.x;
    int fl = *flag;
    int tile0 = blockIdx.x * TILE;
    int segbase = xcc_id() * NBK;

    if (t < NBK) hist[t] = 0;
    __syncthreads();

    // preload: 16B pair loads (int64 path: 2 indices per load, keep lows)
    int dbuf[IPT], sbuf[IPT];
    const int* pw = (const int*)ei;
    if (fl) {
#pragma unroll
        for (int k = 0; k < IPT2; ++k) {
            int e = tile0 + k * (2 * BTH) + 2 * t;
            ulonglong2 dd = *(const ulonglong2*)((const long long*)ei + NE + e);
            ulonglong2 ss = *(const ulonglong2*)((const long long*)ei + e);
            dbuf[2 * k] = (int)dd.x;
            dbuf[2 * k + 1] = (int)dd.y;
            sbuf[2 * k] = (int)ss.x;
            sbuf[2 * k + 1] = (int)ss.y;
        }
    } else {
#pragma unroll
        for (int k = 0; k < IPT2; ++k) {
            int e = tile0 + k * (2 * BTH) + 2 * t;
            uint2 dd = *(const uint2*)(pw + NE + e);
            uint2 ss = *(const uint2*)(pw + e);
            dbuf[2 * k] = (int)dd.x;
            dbuf[2 * k + 1] = (int)dd.y;
            sbuf[2 * k] = (int)ss.x;
            sbuf[2 * k + 1] = (int)ss.y;
        }
    }

    // atomic rank capture from registers.
    // pk = (dlow<<18)|src ; ra = (rank<<9)|bucket  (rank<5120 fits 13 bits)
    unsigned pk[IPT];
    unsigned ra[IPT];
#pragma unroll
    for (int k = 0; k < IPT; ++k) {
        int d = dbuf[k];
        int b = d >> 9;
        int r = atomicAdd(&hist[b], 1);
        pk[k] = ((unsigned)(d & 511) << 18) | (unsigned)sbuf[k];
        ra[k] = ((unsigned)r << 9) | (unsigned)b;
    }
    __syncthreads();

    // exclusive scan of 392 counts: pair-sum + 64-lane shfl scan + wave combine
    int h0 = 0, h1 = 0, p = 0;
    if (t < NBK / 2) {
        h0 = hist[2 * t];
        h1 = hist[2 * t + 1];
        p = h0 + h1;
    }
    int lane = t & 63;
    int w = t >> 6;
    int incl = p;
#pragma unroll
    for (int off = 1; off < 64; off <<= 1) {
        int v = __shfl_up(incl, off, 64);
        if (lane >= off) incl += v;
    }
    if (lane == 63) wsum[w] = incl;
    __syncthreads();
    int wbase = 0;
#pragma unroll
    for (int ww = 0; ww < BTH / 64; ++ww) wbase += (ww < w) ? wsum[ww] : 0;
    int ex = wbase + incl - p;
    if (t < NBK / 2) {
        lofs[2 * t] = ex;
        lofs[2 * t + 1] = ex + h0;
    }
    if (t < NBK) gofs[t] = atomicAdd(&gcur[(segbase + t) * GSTR], hist[t]);
    __syncthreads();

    // stage from regs at lofs[bucket] + rank (no global loads)
#pragma unroll
    for (int k = 0; k < IPT; ++k) {
        int b = (int)(ra[k] & 511u);
        int r = (int)(ra[k] >> 9);
        stage[lofs[b] + r] = pk[k];
    }
    __syncthreads();

    // coalesced write-out; bucket of slot i via seeded search on lofs
    for (int i = t; i < TILE; i += BTH) {
        int b = (i * 313) >> 12;  // ~ i / 13.06 (mean slots per bucket)
        if (b > NBK - 1) b = NBK - 1;
        while (b < NBK - 1 && lofs[b + 1] <= i) ++b;
        while (lofs[b] > i) --b;
        unsigned pack = stage[i];
        int seg = segbase + b;
        int dest = gofs[b] + (i - lofs[b]);
        if (dest < (seg + 1) * SCAP) {
            binned[dest] = pack;
        } else {  // overflow (never in practice)
            int op = atomicAdd(&gcur[NSEG * GSTR], 1);
            if (op < OVFCAP) {
                int d = (b << 9) | (int)(pack >> 18);
                int s = (int)(pack & 0x3FFFF);
                ovf[op] = ((ull)d << 32) | (unsigned)s;
            }
        }
    }
}

// bucket-local counting sort over 8 sub-segments, key = (dlow<<2)|phase(src).
// Single pass: rank captured from cnt atomic, (src, rank|key) in regs;
// scatter into LDS stage; coalesced uint4 write-out. Computes dinv and packed
// phase counts. Fused prep: after write-out, 2 threads/node write the
// block's 512 xph rows (fp16 dinv*x, padded to 16 halves).
__global__ __launch_bounds__(1024, 4) void k_sort(const int* __restrict__ gcur,
                                                  const unsigned* __restrict__ binned,
                                                  const ull* __restrict__ ovf,
                                                  const float* __restrict__ x,
                                                  unsigned* __restrict__ csr,
                                                  float* __restrict__ dinv,
                                                  int* __restrict__ rsg,
                                                  unsigned* __restrict__ spl,
                                                  __half* __restrict__ xph) {
    __shared__ int cnt[2048];
    __shared__ int excl[2048];
    __shared__ int wsum[16];
    __shared__ int nseg[NSUB];
    __shared__ float sdv[512];
    __shared__ unsigned stage[CCAP];      // 88KB sorted bucket staging
    int b = blockIdx.x;
    int t = threadIdx.x;
    cnt[t] = 0;
    cnt[t + 1024] = 0;
    if (t < NSUB) {
        int seg = t * NBK + b;
        nseg[t] = min(gcur[seg * GSTR] - seg * SCAP, SCAP);
    }
    __syncthreads();
    int nov = min(gcur[NSEG * GSTR], OVFCAP);

    // single pass: load + key + rank capture; held in regs (static indexing)
    unsigned srcv[NSUB * SPT];
    unsigned rkv[NSUB * SPT];
#pragma unroll
    for (int s = 0; s < NSUB; ++s) {
        int n = nseg[s];
        int sb = (s * NBK + b) * SCAP;
#pragma unroll
        for (int k = 0; k < SPT; ++k) {
            int i = k * 1024 + t;
            rkv[s * SPT + k] = 0xFFFFFFFFu;
            if (i < n) {
                unsigned pack = binned[sb + i];
                unsigned src = pack & 0x3FFFFu;
                int key = ((int)(pack >> 18) << 2) | phase_of(src);
                int r = atomicAdd(&cnt[key], 1);
                srcv[s * SPT + k] = src;
                rkv[s * SPT + k] = ((unsigned)r << 11) | (unsigned)key;
            }
        }
    }
    __syncthreads();

    // exclusive scan of 2048 counts: pair-sum + 1024-lane scan (16 waves)
    int h0 = cnt[2 * t];
    int h1 = cnt[2 * t + 1];
    int p = h0 + h1;
    int lane = t & 63;
    int w = t >> 6;
    int incl = p;
#pragma unroll
    for (int off = 1; off < 64; off <<= 1) {
        int v = __shfl_up(incl, off, 64);
        if (lane >= off) incl += v;
    }
    if (lane == 63) wsum[w] = incl;
    __syncthreads();
    int wbase = 0;
#pragma unroll
    for (int ww = 0; ww < 16; ++ww) wbase += (ww < w) ? wsum[ww] : 0;
    int ex = wbase + incl - p;
    excl[2 * t] = ex;
    excl[2 * t + 1] = ex + h0;
    __syncthreads();

    // scatter into LDS stage (bucket-relative positions)
#pragma unroll
    for (int c = 0; c < NSUB * SPT; ++c) {
        unsigned rk = rkv[c];
        if (rk != 0xFFFFFFFFu) {
            int key = (int)(rk & 0x7FFu);
            int r = (int)(rk >> 11);
            stage[excl[key] + r] = srcv[c];
        }
    }

    // per-node stats (cnt/excl are stable; independent of stage)
    if (t < 512) {
        int g = (b << 9) + t;
        if (g < NN) {
            int c0 = cnt[4 * t];
            int c1 = cnt[4 * t + 1];
            int c2 = cnt[4 * t + 2];
            int c3 = cnt[4 * t + 3];
            int extra = 0;
            for (int k = 0; k < nov; ++k) extra += ((int)(ovf[k] >> 32) == g);
            float dv = rsqrtf((float)(c0 + c1 + c2 + c3 + extra) + 1.0f);
            dinv[g] = dv;
            sdv[t] = dv;
            rsg[g] = b * CCAP + excl[4 * t];                 // csr row start (absolute)
            spl[g] = (unsigned)c0 | ((unsigned)c1 << 8) |
                     ((unsigned)c2 << 16) | ((unsigned)c3 << 24);
        }
    }
    __syncthreads();

    // coalesced uint4 write-out (pad to 16B; garbage pad stays in-bucket)
    int total = excl[2047] + cnt[2047];
    int tot4 = (total + 3) >> 2;
    const uint4* st4 = (const uint4*)stage;
    uint4* csr4 = (uint4*)(csr + (size_t)b * CCAP);
#pragma unroll
    for (int k = 0; k < (CCAP / 4 + 1023) / 1024; ++k) {
        int i4 = k * 1024 + t;
        if (i4 < tot4) csr4[i4] = st4[i4];
    }

    // fused prep: xph rows for this block's 512 nodes (2 threads per node,
    // 8 halves each). sdv synced by the pre-write-out barrier.
    {
        int n512 = t >> 1;
        int g = (b << 9) + n512;
        if (g < NN) {
            float dv = sdv[n512];
            int cb = 8 * (t & 1);
            const float* xr = x + (size_t)g * IC;
            float v[8];
#pragma unroll
            for (int c = 0; c < 8; c += 2) {
                int ch = cb + c;
                if (ch + 1 < IC) {
                    float2 xx = *(const float2*)(xr + ch);
                    v[c] = dv * xx.x;
                    v[c + 1] = dv * xx.y;
                } else {
                    v[c] = 0.0f;
                    v[c + 1] = 0.0f;
                }
            }
            __half2 p0 = __floats2half2_rn(v[0], v[1]);
            __half2 p1 = __floats2half2_rn(v[2], v[3]);
            __half2 p2 = __floats2half2_rn(v[4], v[5]);
            __half2 p3 = __floats2half2_rn(v[6], v[7]);
            uint4 pk4;
            pk4.x = *(unsigned*)&p0;
            pk4.y = *(unsigned*)&p1;
            pk4.z = *(unsigned*)&p2;
            pk4.w = *(unsigned*)&p3;
            *(uint4*)(xph + (size_t)g * 16 + cb) = pk4;
        }
    }
}

// Fused layer-1: full csr row gather + self row + overflow fixup + fused MLP.
// 8 lanes per node (qc channel half x eh edge quarter, 16B uint4 gathers);
// shfl_xor(2,4) sums; padded LDS tile exchanges agg; 2 hidden units per
// lane, shfl_xor(1,2,4) combines the output dot. Writes only h2bp/selfout.
__global__ __launch_bounds__(256) void k_agg1f(const int* __restrict__ rsg,
                                               const unsigned* __restrict__ spl,
                                               const unsigned* __restrict__ csr,
                                               const __half* __restrict__ xph,
                                               const int* __restrict__ gcur,
                                               const ull* __restrict__ ovf,
                                               const float* __restrict__ dinv,
                                               const float* __restrict__ W1,
                                               const float* __restrict__ b1,
                                               const float* __restrict__ W2,
                                               const float* __restrict__ b2,
                                               float2* __restrict__ h2bp,
                                               float2* __restrict__ selfout) {
    __shared__ float sW1[IC * HC];
    __shared__ float sb1[HC];
    __shared__ float sW2[HC * OC];
    __shared__ float sb2[OC];
    __shared__ float sAgg[32][17];  // +1 pad: spread rows across banks
    int t = threadIdx.x;
    if (t < IC * HC) sW1[t] = W1[t];
    if (t < HC) sb1[t] = b1[t];
    if (t < HC * OC) sW2[t] = W2[t];
    if (t < OC) sb2[t] = b2[t];

    int g = t >> 3;
    int h = t & 7;
    int qc = h & 1;
    int eh = h >> 1;
    int i = blockIdx.x * 32 + g;   // NN = 6250*32 exactly
    unsigned sp = spl[i];
    int tot = (int)(sp & 255u) + (int)((sp >> 8) & 255u) +
              (int)((sp >> 16) & 255u) + (int)(sp >> 24);
    int beg = rsg[i];
    int end = beg + tot;

    float av[8];
#pragma unroll
    for (int c = 0; c < 8; ++c) av[c] = 0.0f;
    int j = beg + eh;
    int s0 = (j < end) ? (int)csr[j] : -1;
    int s1 = (j + 4 < end) ? (int)csr[j + 4] : -1;
    while (j < end) {
        int jn = j + 8;
        int n0 = (jn < end) ? (int)csr[jn] : -1;
        int n1 = (jn + 4 < end) ? (int)csr[jn + 4] : -1;
        uint4 u0 = *(const uint4*)(xph + (size_t)s0 * 16 + 8 * qc);
        acc8(av, u0);
        if (s1 >= 0) {
            uint4 u1 = *(const uint4*)(xph + (size_t)s1 * 16 + 8 * qc);
            acc8(av, u1);
        }
        s0 = n0;
        s1 = n1;
        j = jn;
    }

    // self row folded pre-combine by eh==0 lanes (once per qc half)
    if (eh == 0) {
        uint4 us = *(const uint4*)(xph + (size_t)i * 16 + 8 * qc);
        acc8(av, us);
    }
#pragma unroll
    for (int c = 0; c < 8; ++c) av[c] += __shfl_xor(av[c], 2);
#pragma unroll
    for (int c = 0; c < 8; ++c) av[c] += __shfl_xor(av[c], 4);

    float dv = dinv[i];
    if (eh == 0) {
        // overflow fixup (nov==0 in practice)
        int nov = min(gcur[NSEG * GSTR], OVFCAP);
        for (int k = 0; k < nov; ++k) {
            ull e = ovf[k];
            if ((int)(e >> 32) == i) {
                int s = (int)(e & 0xFFFFFFFFu);
#pragma unroll
                for (int c = 0; c < 8; ++c)
                    av[c] += __half2float(xph[(size_t)s * 16 + 8 * qc + c]);
            }
        }
#pragma unroll
        for (int c = 0; c < 8; ++c) sAgg[g][8 * qc + c] = dv * av[c];
    }
    __syncthreads();

    // MLP: lane l8 = t&7 computes hidden units 2*l8, 2*l8+1 (sAgg row is an
    // LDS broadcast across the node's 8 lanes).
    int l8 = t & 7;
    float o0 = 0.0f, o1 = 0.0f;
#pragma unroll
    for (int f2 = 0; f2 < 2; ++f2) {
        int f = 2 * l8 + f2;
        float a = sb1[f];
#pragma unroll
        for (int c = 0; c < IC; ++c) a = fmaf(sAgg[g][c], sW1[c * HC + f], a);
        a = fmaxf(a, 0.0f);
        o0 = fmaf(a, sW2[f * OC + 0], o0);
        o1 = fmaf(a, sW2[f * OC + 1], o1);
    }
    o0 += __shfl_xor(o0, 1);
    o1 += __shfl_xor(o1, 1);
    o0 += __shfl_xor(o0, 2);
    o1 += __shfl_xor(o1, 2);
    o0 += __shfl_xor(o0, 4);
    o1 += __shfl_xor(o1, 4);
    if (l8 == 0) {
        h2bp[i] = make_float2(o0 * dv, o1 * dv);  // dinv-prescaled for layer 2
        selfout[i] = make_float2(o0 * dv * dv + sb2[0], o1 * dv * dv + sb2[1]);
    }
}

// layer-2: out[i] = selfout[i] + dinv[i] * (sum h2bp[src] + ovf matches).
// 8 lanes per node, depth-1 csr pipeline; shfl_xor(1,2,4) combine.
__global__ __launch_bounds__(256) void k_agg2(const int* __restrict__ rsg,
                                              const unsigned* __restrict__ spl,
                                              const unsigned* __restrict__ csr,
                                              const int* __restrict__ gcur,
                                              const ull* __restrict__ ovf,
                                              const float* __restrict__ dinv,
                                              const float2* __restrict__ h2bp,
                                              const float2* __restrict__ selfout,
                                              float2* __restrict__ out) {
    int tt = blockIdx.x * 256 + threadIdx.x;
    int i = tt >> 3;
    int h = tt & 7;
    if (i >= NN) return;
    unsigned sp = spl[i];
    int tot = (int)(sp & 255u) + (int)((sp >> 8) & 255u) +
              (int)((sp >> 16) & 255u) + (int)(sp >> 24);
    int beg = rsg[i];
    int end = beg + tot;
    float ax = 0.0f, ay = 0.0f;
    int j = beg + h;
    int s0 = (j < end) ? (int)csr[j] : -1;
    int s1 = (j + 8 < end) ? (int)csr[j + 8] : -1;
    while (j < end) {
        int jn = j + 16;
        int n0 = (jn < end) ? (int)csr[jn] : -1;
        int n1 = (jn + 8 < end) ? (int)csr[jn + 8] : -1;
        float2 h0 = h2bp[s0];
        ax += h0.x;
        ay += h0.y;
        if (s1 >= 0) {
            float2 h1 = h2bp[s1];
            ax += h1.x;
            ay += h1.y;
        }
        s0 = n0;
        s1 = n1;
        j = jn;
    }
    ax += __shfl_xor(ax, 1);
    ay += __shfl_xor(ay, 1);
    ax += __shfl_xor(ax, 2);
    ay += __shfl_xor(ay, 2);
    ax += __shfl_xor(ax, 4);
    ay += __shfl_xor(ay, 4);
    if (h == 0) {
        // overflow fixup (nov==0 in practice); h2bp already dinv[src]-prescaled
        int nov = min(gcur[NSEG * GSTR], OVFCAP);
        for (int k = 0; k < nov; ++k) {
            ull e = ovf[k];
            if ((int)(e >> 32) == i) {
                float2 hh = h2bp[(int)(e & 0xFFFFFFFFu)];
                ax += hh.x;
                ay += hh.y;
            }
        }
        float dv = dinv[i];
        float2 so = selfout[i];
        out[i] = make_float2(so.x + dv * ax, so.y + dv * ay);
    }
}

extern "C" void kernel_launch(void* const* d_in, const int* in_sizes, int n_in,
                              void* d_out, int out_size, void* d_ws, size_t ws_size,
                              hipStream_t stream) {
    const float* x = (const float*)d_in[0];
    const void* ei = d_in[1];
    // d_in[2] = edge_attr (unused)
    const float* W1 = (const float*)d_in[3];
    const float* b1 = (const float*)d_in[4];
    const float* W2 = (const float*)d_in[5];
    const float* b2 = (const float*)d_in[6];
    float* out = (float*)d_out;

    ull* ovf = (ull*)d_ws;                              // OVFCAP       (0.5MB)
    int* gcur = (int*)(ovf + OVFCAP);                   // (NSEG+5)*16 ints
    int* flag = gcur + (NSEG + 5) * GSTR;               // 4
    int* rsg = flag + 4;                                // NN
    unsigned* spl = (unsigned*)(rsg + NN);              // NN
    float* dinv = (float*)(spl + NN);                   // NN
    __half* xph = (__half*)(dinv + NN);                 // NN*16 halves (6.4MB)
    float2* h2bp = (float2*)(xph + (size_t)NN * 16);    // NN
    float2* selfout = h2bp + NN;                        // NN
    unsigned* binned = (unsigned*)(selfout + NN);       // NSEG*SCAP    (35.3MB)
    unsigned* csr = binned + (size_t)NSEG * SCAP;       // NBK*CCAP     (35.3MB)

    k_init<<<(NSEG + 5 + 255) / 256, 256, 0, stream>>>(gcur, ei, flag);
    k_binA<<<NTILE, BTH, 0, stream>>>(ei, flag, gcur, binned, ovf);
    k_sort<<<NBK, 1024, 0, stream>>>(gcur, binned, ovf, x, csr, dinv, rsg, spl, xph);
    k_agg1f<<<NM, 256, 0, stream>>>(rsg, spl, csr, xph, gcur, ovf, dinv,
                                    W1, b1, W2, b2, h2bp, selfout);
    k_agg2<<<(NN * 8 + 255) / 256, 256, 0, stream>>>(rsg, spl, csr, gcur, ovf, dinv,
                                                     h2bp, selfout, (float2*)out);
}